// Round 5
// baseline (342.475 us; speedup 1.0000x reference)
//
#include <hip/hip_runtime.h>
#include <math.h>

#define MQ 1000
#define PI_F 3.14159265358979323846f
#define EPSF 1e-12f
#define DYF  ((float)(0.998/999.0))   // main y-grid step
#define DY2F ((float)(0.999/999.0))   // disconnected y2-grid step

// fast HW approx ops (v_rcp_f32 / v_rsq_f32 / v_sqrt_f32, ~1 ulp)
__device__ __forceinline__ float frcp(float x)  { return __builtin_amdgcn_rcpf(x); }
__device__ __forceinline__ float frsq(float x)  { return __builtin_amdgcn_rsqf(x); }
__device__ __forceinline__ float fsqrt(float x) { return __builtin_amdgcn_sqrtf(x); }

// ws layout: [0]=zs_max [1]=L_max [2]=zs_crit [3]=L_crit [4..20]=L_table[0..16]
// L_table[i] = integrate_L(zs_max * i/16);  L_table[0]=0, L_table[16]=L_max.

// ---------------------------------------------------------------------------
// f(z) = 1 + q1 z + q2 z^2 + q3 z^3 + (q4 + cf4 ln z) z^4
// s(z) = 1 + e1 z + e2 z^2 + e3 z^3 + e4 z^4 ;  df = 4(f - s)/z
// eval_b_ = P(z)^2, P = 1 + b0 z + b1 z^2 + p3 z^3, p3 = a0+a1-b0-b1
// g = P^2/(1-z^4);  z dg/g = 2 z P'/P + 4 z^4/(1-z^4);  sqrt(g) = P rsqrt(1-z^4)
// ---------------------------------------------------------------------------
struct Co {
    float q1, q2, q3, q4, cf4;
    float e1, e2, e3, e4;
    float b0, b1, p3;
    float coef;
};

__device__ __forceinline__ Co make_co(const float* a, const float* b, const float* lc) {
    Co c;
    float a0 = a[0], a1 = a[1];
    float cf1 = -8.f * a0 / 3.f;
    float cf2 = -2.f * (2.f * a1 + a0 * a0);
    float cf3 = -8.f * a0 * a1;
    c.cf4 = -4.f * a1 * a1;
    c.q1 = -cf1; c.q2 = -cf2; c.q3 = -cf3; c.q4 = cf1 + cf2 + cf3 - 1.f;
    c.e1 = 2.f * a0;
    c.e2 = 2.f * a1 + a0 * a0;
    c.e3 = 2.f * a0 * a1;
    c.e4 = a1 * a1;
    c.b0 = b[0]; c.b1 = b[1];
    c.p3 = a0 + a1 - b[0] - b[1];
    c.coef = expf(lc[0]);
    return c;
}

struct Uni { float zs, fs, rfs, A4; };

__device__ __forceinline__ Uni make_uni(const Co& c, float zs) {
    Uni U; U.zs = zs;
    float z = zs;
    float lg = __logf(z);
    float t4 = c.q4 + c.cf4 * lg;
    float fz = 1.f + z * (c.q1 + z * (c.q2 + z * (c.q3 + z * t4)));
    float s  = 1.f + z * (c.e1 + z * (c.e2 + z * (c.e3 + z * c.e4)));
    U.fs = fz;
    U.rfs = frcp(fz);
    float dfs = 4.f * (fz - s) * frcp(z);
    U.A4 = zs * dfs * U.rfs - 2.f;     // (zs dfs/fs + 2) - 4
    return U;
}

// L and dL integrands at one point; y and u = 1-y^2 passed in.
__device__ __forceinline__ void point_LdL(const Co& c, const Uni& U,
                                          float y, float u,
                                          float& iL, float& iD) {
    float u2  = u * u;
    float ru2 = frcp(u2);
    float ru4 = ru2 * ru2;
    float z  = U.zs * u;
    float z2 = z * z, z4 = z2 * z2;
    float lg = __logf(z);
    float t4 = c.q4 + c.cf4 * lg;
    float fz = 1.f + z * (c.q1 + z * (c.q2 + z * (c.q3 + z * t4)));
    float s  = 1.f + z * (c.e1 + z * (c.e2 + z * (c.e3 + z * c.e4)));
    float P  = 1.f + z * (c.b0 + z * (c.b1 + z * c.p3));
    float dP = c.b0 + z * (2.f * c.b1 + z * (3.f * c.p3));
    float D  = 1.f - z4;
    float rsqD = frsq(D);
    float rcpD = rsqD * rsqD;
    float rcpP = frcp(P);
    float zdgg = 2.f * z * dP * rcpP + 4.f * z4 * rcpD;   // z dg / g
    float F4 = fz * U.rfs * ru4;                          // r4 * f/fs
    float S4 = s  * U.rfs * ru4;
    float den = fmaxf(F4 - 1.f, EPSF);                    // argL == dL denominator
    float rs  = frsq(den);
    float sqg = P * rsqD;                                 // sqrt(g)
    float t1  = sqg * rs;
    iL = t1 * y;
    float t = F4 * (U.A4 + zdgg) + 4.f * S4 - 2.f - zdgg;
    float rs2 = rs * rs;
    iD = t * (2.f * y) * (t1 * rs2);                      // sqrt(1-z/zs) = y
}

// connected-V integrand
__device__ __forceinline__ float point_Vc(const Co& c, const Uni& U,
                                          float y, float u) {
    float u2  = u * u;
    float u4  = u2 * u2;
    float ru2 = frcp(u2);                                 // 1/w
    float z  = U.zs * u;
    float z2 = z * z, z4 = z2 * z2;
    float lg = __logf(z);
    float t4 = c.q4 + c.cf4 * lg;
    float fz = 1.f + z * (c.q1 + z * (c.q2 + z * (c.q3 + z * t4)));
    float P  = 1.f + z * (c.b0 + z * (c.b1 + z * c.p3));
    float D  = 1.f - z4;
    float rsqD = frsq(D);
    float rcpD = rsqD * rsqD;
    float fg = fz * P * P * rcpD;
    float sqfg = fsqrt(fmaxf(fg, EPSF));
    float rfz = frcp(fz);
    float arg = fmaxf(1.f - u4 * U.fs * rfz, EPSF);       // 1 - w^2/fof
    float t = frsq(arg) - 1.f;
    return sqfg * ru2 * t * y;
}

// disconnected-V integrand on the y2 grid
__device__ __forceinline__ float point_Vd(const Co& c, const Uni& U, float y2) {
    float z  = 1.f - (1.f - U.zs) * y2;
    float z2 = z * z, z4 = z2 * z2;
    float lg = __logf(z);
    float t4 = c.q4 + c.cf4 * lg;
    float fz = 1.f + z * (c.q1 + z * (c.q2 + z * (c.q3 + z * t4)));
    float P  = 1.f + z * (c.b0 + z * (c.b1 + z * c.p3));
    float D  = 1.f - z4;
    float rsqD = frsq(D);
    float fg = fz * P * P * (rsqD * rsqD);
    float sq = fsqrt(fmaxf(fg, EPSF));
    float rz = frcp(z);
    return sq * rz * rz;
}

// trapz over extended grid yy=[0, y..., 1], ii=[v0, integ..., 0]
__device__ __forceinline__ float trapz_ext(float S, float i0, float i1, float iN) {
    float slope = (i1 - i0) * frcp(DYF);
    float v0 = i0 - slope * 0.001f;
    float yLast = 0.001f + 999.f * DYF;
    return DYF * (S - 0.5f * (i0 + iN))
         + 0.5f * (v0 + i0) * 0.001f
         + 0.5f * iN * (1.f - yLast);
}

__device__ __forceinline__ float trapz_d(float S, float q0, float qN) {
    return 0.5f * (1.f + q0) * 0.001f + DY2F * (S - 0.5f * (q0 + qN));
}

// ---------------------------------------------------------------------------
// Wave-local quadratures (16 points/lane; j = lane + 64k; j==0,1 -> k=0 lanes
// 0,1; j==999 -> k=15 lane 39).  All lanes return the same value.
// ---------------------------------------------------------------------------
__device__ __forceinline__ float wave_L(const Co& c, const Uni& U, int lane) {
    float sL = 0.f, l0 = 0.f, lN = 0.f;
#pragma unroll
    for (int k = 0; k < 16; ++k) {
        if (k < 15 || lane < 40) {
            int j = lane + 64 * k;
            float y = fmaf((float)j, DYF, 0.001f);
            float u = 1.f - y * y;
            float iL, iD;
            point_LdL(c, U, y, u, iL, iD);
            sL += iL;
            if (k == 0)  l0 = iL;
            if (k == 15) lN = iL;
        }
    }
#pragma unroll
    for (int o = 32; o > 0; o >>= 1) sL += __shfl_xor(sL, o, 64);
    float i0 = __shfl(l0, 0, 64), i1 = __shfl(l0, 1, 64), iN = __shfl(lN, 39, 64);
    return 4.f * U.zs * trapz_ext(sL, i0, i1, iN) / PI_F;
}

__device__ __forceinline__ float wave_dL(const Co& c, const Uni& U, int lane) {
    float sD = 0.f, d0 = 0.f, dN = 0.f;
#pragma unroll
    for (int k = 0; k < 16; ++k) {
        if (k < 15 || lane < 40) {
            int j = lane + 64 * k;
            float y = fmaf((float)j, DYF, 0.001f);
            float u = 1.f - y * y;
            float iL, iD;
            point_LdL(c, U, y, u, iL, iD);
            sD += iD;
            if (k == 0)  d0 = iD;
            if (k == 15) dN = iD;
        }
    }
#pragma unroll
    for (int o = 32; o > 0; o >>= 1) sD += __shfl_xor(sD, o, 64);
    float e0 = __shfl(d0, 0, 64), e1 = __shfl(d0, 1, 64), eN = __shfl(dN, 39, 64);
    return trapz_ext(sD, e0, e1, eN) / PI_F;
}

__device__ __forceinline__ float wave_V(const Co& c, const Uni& U, int lane) {
    float sc = 0.f, sd = 0.f, c0 = 0.f, cN = 0.f, q0 = 0.f, qN = 0.f;
#pragma unroll
    for (int k = 0; k < 16; ++k) {
        if (k < 15 || lane < 40) {
            int j = lane + 64 * k;
            float y = fmaf((float)j, DYF, 0.001f);
            float u = 1.f - y * y;
            float vc = point_Vc(c, U, y, u);
            float y2 = fmaf((float)j, DY2F, 0.001f);
            float vd = point_Vd(c, U, y2);
            sc += vc; sd += vd;
            if (k == 0)  { c0 = vc; q0 = vd; }
            if (k == 15) { cN = vc; qN = vd; }
        }
    }
#pragma unroll
    for (int o = 32; o > 0; o >>= 1) {
        sc += __shfl_xor(sc, o, 64);
        sd += __shfl_xor(sd, o, 64);
    }
    float i0 = __shfl(c0, 0, 64), i1 = __shfl(c0, 1, 64), iN = __shfl(cN, 39, 64);
    float p0 = __shfl(q0, 0, 64), pN = __shfl(qN, 39, 64);
    float Vc = c.coef * PI_F * 4.f * trapz_ext(sc, i0, i1, iN) * frcp(U.zs);
    float Vd = c.coef * PI_F * 2.f * (1.f - U.zs) * trapz_d(sd, p0, pN);
    return Vc - Vd;
}

// ---------------------------------------------------------------------------
// Kernel 1: 8-section searches (wave-per-candidate, 512 threads = 8 waves),
// then one parallel batch of 17 L-quadratures (inverse table + L_max + L_crit).
// ---------------------------------------------------------------------------
__global__ __launch_bounds__(512) void solve_scalars_kernel(
        const float* a, const float* b, const float* lc, float* ws) {
    __shared__ float cand[8];
    __shared__ float Lres[17];
    Co c = make_co(a, b, lc);
    int t = threadIdx.x;
    int lane = t & 63, w = t >> 6;

    // --- 8-section 1: root of dL on [0.001, 0.999]; pred = dL < 0 ---
    float lo = 0.001f, hi = 0.999f;
    for (int round = 0; round < 9; ++round) {
        float step = (hi - lo) * 0.125f;
        if (w < 7) {
            float mid = fmaf((float)(w + 1), step, lo);
            Uni U = make_uni(c, mid);
            float v = wave_dL(c, U, lane);
            if (lane == 0) cand[w] = v;
        }
        __syncthreads();
        int istar = 8;
        for (int i = 1; i <= 7; ++i) {
            if (cand[i - 1] < 0.f) { istar = i; break; }
        }
        __syncthreads();
        if (istar == 8) {
            lo = fmaf(7.f, step, lo);
        } else {
            float nlo = fmaf((float)(istar - 1), step, lo);
            hi = fmaf((float)istar, step, lo);
            lo = nlo;
        }
    }
    float zs_max = 0.5f * (lo + hi);

    // --- 8-section 2: root of -V on [0.001, zs_max]; pred = V > 0 ---
    lo = 0.001f; hi = zs_max;
    for (int round = 0; round < 9; ++round) {
        float step = (hi - lo) * 0.125f;
        if (w < 7) {
            float mid = fmaf((float)(w + 1), step, lo);
            Uni U = make_uni(c, mid);
            float v = wave_V(c, U, lane);
            if (lane == 0) cand[w] = v;
        }
        __syncthreads();
        int istar = 8;
        for (int i = 1; i <= 7; ++i) {
            if (cand[i - 1] > 0.f) { istar = i; break; }
        }
        __syncthreads();
        if (istar == 8) {
            lo = fmaf(7.f, step, lo);
        } else {
            float nlo = fmaf((float)(istar - 1), step, lo);
            hi = fmaf((float)istar, step, lo);
            lo = nlo;
        }
    }
    float zs_crit = 0.5f * (lo + hi);

    // --- batch: 17 L-quadratures.  q=0..14 -> table zs_max*(q+1)/16,
    //     q=15 -> zs_max (L_max), q=16 -> zs_crit (L_crit). ---
#pragma unroll
    for (int r = 0; r < 3; ++r) {
        int q = w + 8 * r;
        if (q < 17) {
            float zq = (q == 15) ? zs_max
                     : (q == 16) ? zs_crit
                     : zs_max * (float)(q + 1) * (1.f / 16.f);
            Uni U = make_uni(c, zq);
            float Lq = wave_L(c, U, lane);
            if (lane == 0) Lres[q] = Lq;
        }
    }
    __syncthreads();
    if (t == 0) {
        ws[0] = zs_max; ws[1] = Lres[15]; ws[2] = zs_crit; ws[3] = Lres[16];
        ws[4] = 0.f;
        for (int i = 1; i <= 15; ++i) ws[4 + i] = Lres[i - 1];
        ws[20] = Lres[15];
    }
}

// ---------------------------------------------------------------------------
// Kernel 2: per-element Newton + V.  One wave per element.  Initial guess by
// piecewise-linear inversion of the 17-entry L-table -> ~3-5 Newton steps.
// ---------------------------------------------------------------------------
__global__ __launch_bounds__(256) void newton_v_kernel(
        const float* Ls, const float* a, const float* b, const float* lc,
        const float* ws, float* out, int B) {
    int wid = (blockIdx.x * blockDim.x + threadIdx.x) >> 6;
    int lane = threadIdx.x & 63;
    if (wid >= B) return;

    Co c = make_co(a, b, lc);
    float zs_max = ws[0], L_crit = ws[3];
    float Lq = Ls[wid];
    bool valid = Lq < L_crit;
    float L_eff = valid ? Lq : 0.5f * L_crit;

    // inverse-table init: last segment i with L_eff >= table[i]
    float dz = zs_max * (1.f / 16.f);
    float zlo = 0.f, Ll = 0.f, Lh = ws[5];
#pragma unroll
    for (int i = 1; i < 16; ++i) {
        float Li = ws[4 + i];
        float Ln = ws[5 + i];
        bool go = (L_eff >= Li);
        zlo = go ? dz * (float)i : zlo;
        Ll  = go ? Li : Ll;
        Lh  = go ? Ln : Lh;
    }
    float frac = (L_eff - Ll) * frcp(fmaxf(Lh - Ll, 1e-20f));
    frac = fminf(fmaxf(frac, 0.f), 1.f);
    float zs = fminf(fmaxf(fmaf(frac, dz, zlo), 1e-4f), 0.9995f);
    float zs_prev = -1.f;

    for (int step = 0; step < 25; ++step) {
        Uni U = make_uni(c, zs);
        float sL = 0.f, sD = 0.f, l0 = 0.f, d0 = 0.f, lN = 0.f, dN = 0.f;
#pragma unroll
        for (int k = 0; k < 16; ++k) {
            if (k < 15 || lane < 40) {     // j < 1000; constant-true for k<15
                int j = lane + 64 * k;
                float y = fmaf((float)j, DYF, 0.001f);
                float u = 1.f - y * y;
                float iL, iD;
                point_LdL(c, U, y, u, iL, iD);
                sL += iL; sD += iD;
                if (k == 0)  { l0 = iL; d0 = iD; }
                if (k == 15) { lN = iL; dN = iD; }
            }
        }
#pragma unroll
        for (int o = 32; o > 0; o >>= 1) {
            sL += __shfl_xor(sL, o, 64);
            sD += __shfl_xor(sD, o, 64);
        }
        float i0 = __shfl(l0, 0, 64), i1 = __shfl(l0, 1, 64), iN = __shfl(lN, 39, 64);
        float e0 = __shfl(d0, 0, 64), e1 = __shfl(d0, 1, 64), eN = __shfl(dN, 39, 64);
        float Lz = 4.f * zs * trapz_ext(sL, i0, i1, iN) / PI_F;
        float dL = trapz_ext(sD, e0, e1, eN) / PI_F;
        float nzs = fminf(fmaxf(zs - (Lz - L_eff) * frcp(dL), 1e-4f), 0.9995f);
        if (nzs == zs || nzs == zs_prev) break;   // fixed point or 2-cycle
        zs_prev = zs;
        zs = nzs;
    }

    // V(zs)
    Uni U = make_uni(c, zs);
    float V = wave_V(c, U, lane);
    if (lane == 0) out[wid] = valid ? V : 0.f;
}

// ---------------------------------------------------------------------------
extern "C" void kernel_launch(void* const* d_in, const int* in_sizes, int n_in,
                              void* d_out, int out_size, void* d_ws, size_t ws_size,
                              hipStream_t stream) {
    const float* Ls = (const float*)d_in[0];
    const float* a  = (const float*)d_in[1];
    const float* b  = (const float*)d_in[2];
    const float* lc = (const float*)d_in[3];
    float* out = (float*)d_out;
    float* ws  = (float*)d_ws;
    int B = in_sizes[0];

    solve_scalars_kernel<<<1, 512, 0, stream>>>(a, b, lc, ws);

    int blocks = (B + 3) / 4;   // 4 waves (elements) per 256-thread block
    newton_v_kernel<<<blocks, 256, 0, stream>>>(Ls, a, b, lc, ws, out, B);
}

// Round 6
// 310.241 us; speedup vs baseline: 1.1039x; 1.1039x over previous
//
#include <hip/hip_runtime.h>
#include <math.h>

#define MQ 1000
#define PI_F 3.14159265358979323846f
#define EPSF 1e-12f
#define DYF  ((float)(0.998/999.0))   // main y-grid step
#define DY2F ((float)(0.999/999.0))   // disconnected y2-grid step (= 0.001)

// fast HW approx ops (v_rcp_f32 / v_rsq_f32 / v_sqrt_f32, ~1 ulp)
__device__ __forceinline__ float frcp(float x)  { return __builtin_amdgcn_rcpf(x); }
__device__ __forceinline__ float frsq(float x)  { return __builtin_amdgcn_rsqf(x); }
__device__ __forceinline__ float fsqrt(float x) { return __builtin_amdgcn_sqrtf(x); }

// ws layout: [0]=zs_max [1]=L_max [2]=zs_crit [3]=L_crit

// ---------------------------------------------------------------------------
// f(z) = 1 + q1 z + q2 z^2 + q3 z^3 + (q4 + cf4 ln z) z^4
// s(z) = 1 + e1 z + e2 z^2 + e3 z^3 + e4 z^4 ;  df = 4(f - s)/z
// eval_b_ = P(z)^2, P = 1 + b0 z + b1 z^2 + p3 z^3, p3 = a0+a1-b0-b1
// g = P^2/(1-z^4);  z dg/g = 2 z P'/P + 4 z^4/(1-z^4);  sqrt(g) = P rsqrt(1-z^4)
// ---------------------------------------------------------------------------
struct Co {
    float q1, q2, q3, q4, cf4;
    float e1, e2, e3, e4;
    float b0, b1, p3;
    float coef;
};

__device__ __forceinline__ Co make_co(const float* a, const float* b, const float* lc) {
    Co c;
    float a0 = a[0], a1 = a[1];
    float cf1 = -8.f * a0 / 3.f;
    float cf2 = -2.f * (2.f * a1 + a0 * a0);
    float cf3 = -8.f * a0 * a1;
    c.cf4 = -4.f * a1 * a1;
    c.q1 = -cf1; c.q2 = -cf2; c.q3 = -cf3; c.q4 = cf1 + cf2 + cf3 - 1.f;
    c.e1 = 2.f * a0;
    c.e2 = 2.f * a1 + a0 * a0;
    c.e3 = 2.f * a0 * a1;
    c.e4 = a1 * a1;
    c.b0 = b[0]; c.b1 = b[1];
    c.p3 = a0 + a1 - b[0] - b[1];
    c.coef = expf(lc[0]);
    return c;
}

struct Uni { float zs, fs, rfs, A4; };

__device__ __forceinline__ Uni make_uni(const Co& c, float zs) {
    Uni U; U.zs = zs;
    float z = zs;
    float lg = __logf(z);
    float t4 = c.q4 + c.cf4 * lg;
    float fz = 1.f + z * (c.q1 + z * (c.q2 + z * (c.q3 + z * t4)));
    float s  = 1.f + z * (c.e1 + z * (c.e2 + z * (c.e3 + z * c.e4)));
    U.fs = fz;
    U.rfs = frcp(fz);
    float dfs = 4.f * (fz - s) * frcp(z);
    U.A4 = zs * dfs * U.rfs - 2.f;     // (zs dfs/fs + 2) - 4
    return U;
}

// L and dL integrands at one point; y and u = 1-y^2 passed in.
__device__ __forceinline__ void point_LdL(const Co& c, const Uni& U,
                                          float y, float u,
                                          float& iL, float& iD) {
    float u2  = u * u;
    float ru2 = frcp(u2);
    float ru4 = ru2 * ru2;
    float z  = U.zs * u;
    float z2 = z * z, z4 = z2 * z2;
    float lg = __logf(z);
    float t4 = c.q4 + c.cf4 * lg;
    float fz = 1.f + z * (c.q1 + z * (c.q2 + z * (c.q3 + z * t4)));
    float s  = 1.f + z * (c.e1 + z * (c.e2 + z * (c.e3 + z * c.e4)));
    float P  = 1.f + z * (c.b0 + z * (c.b1 + z * c.p3));
    float dP = c.b0 + z * (2.f * c.b1 + z * (3.f * c.p3));
    float D  = 1.f - z4;
    float rsqD = frsq(D);
    float rcpD = rsqD * rsqD;
    float rcpP = frcp(P);
    float zdgg = 2.f * z * dP * rcpP + 4.f * z4 * rcpD;   // z dg / g
    float F4 = fz * U.rfs * ru4;                          // r4 * f/fs
    float S4 = s  * U.rfs * ru4;
    float den = fmaxf(F4 - 1.f, EPSF);                    // argL == dL denominator
    float rs  = frsq(den);
    float sqg = P * rsqD;                                 // sqrt(g)
    float t1  = sqg * rs;
    iL = t1 * y;
    float t = F4 * (U.A4 + zdgg) + 4.f * S4 - 2.f - zdgg;
    float rs2 = rs * rs;
    iD = t * (2.f * y) * (t1 * rs2);                      // sqrt(1-z/zs) = y
}

// connected-V integrand
__device__ __forceinline__ float point_Vc(const Co& c, const Uni& U,
                                          float y, float u) {
    float u2  = u * u;
    float u4  = u2 * u2;
    float ru2 = frcp(u2);                                 // 1/w
    float z  = U.zs * u;
    float z2 = z * z, z4 = z2 * z2;
    float lg = __logf(z);
    float t4 = c.q4 + c.cf4 * lg;
    float fz = 1.f + z * (c.q1 + z * (c.q2 + z * (c.q3 + z * t4)));
    float P  = 1.f + z * (c.b0 + z * (c.b1 + z * c.p3));
    float D  = 1.f - z4;
    float rsqD = frsq(D);
    float rcpD = rsqD * rsqD;
    float fg = fz * P * P * rcpD;
    float sqfg = fsqrt(fmaxf(fg, EPSF));
    float rfz = frcp(fz);
    float arg = fmaxf(1.f - u4 * U.fs * rfz, EPSF);       // 1 - w^2/fof
    float t = frsq(arg) - 1.f;
    return sqfg * ru2 * t * y;
}

// disconnected-V integrand on the y2 grid
__device__ __forceinline__ float point_Vd(const Co& c, const Uni& U, float y2) {
    float z  = 1.f - (1.f - U.zs) * y2;
    float z2 = z * z, z4 = z2 * z2;
    float lg = __logf(z);
    float t4 = c.q4 + c.cf4 * lg;
    float fz = 1.f + z * (c.q1 + z * (c.q2 + z * (c.q3 + z * t4)));
    float P  = 1.f + z * (c.b0 + z * (c.b1 + z * c.p3));
    float D  = 1.f - z4;
    float rsqD = frsq(D);
    float fg = fz * P * P * (rsqD * rsqD);
    float sq = fsqrt(fmaxf(fg, EPSF));
    float rz = frcp(z);
    return sq * rz * rz;
}

// trapz over extended grid yy=[0, y..., 1], ii=[v0, integ..., 0]
__device__ __forceinline__ float trapz_ext(float S, float i0, float i1, float iN) {
    float slope = (i1 - i0) * frcp(DYF);
    float v0 = i0 - slope * 0.001f;
    float yLast = 0.001f + 999.f * DYF;
    return DYF * (S - 0.5f * (i0 + iN))
         + 0.5f * (v0 + i0) * 0.001f
         + 0.5f * iN * (1.f - yLast);
}

__device__ __forceinline__ float trapz_d(float S, float q0, float qN) {
    return 0.5f * (1.f + q0) * 0.001f + DY2F * (S - 0.5f * (q0 + qN));
}

// ---------------------------------------------------------------------------
// Kernel 1: scalar bisections.  1024 threads = 16 waves, ONE point per thread
// (shortest dependency chain; 16 waves hide rcp/rsq/log latency), 2 barriers
// per quadrature.  Iteration counts trimmed: zs_max err ~8e-6 is harmless
// (dL(zs_max)=0 so L_max is first-order insensitive; zs_max only bounds
// search 2); zs_crit err ~2e-7 -> L_crit err ~2e-7 (validity flips only for
// Ls within that of the cut, where V ~ 0).
// ---------------------------------------------------------------------------
__global__ __launch_bounds__(1024) void solve_scalars_kernel(
        const float* a, const float* b, const float* lc, float* ws) {
    __shared__ float pA[16], pB[16], spec[6];
    Co c = make_co(a, b, lc);
    int t = threadIdx.x;
    int lane = t & 63, w = t >> 6;
    bool act = (t < MQ);
    float y = fmaf((float)t, DYF, 0.001f);
    float u = 1.f - y * y;
    float y2 = fmaf((float)t, DY2F, 0.001f);

    // --- bisection 1: root of dL on [0.001, 0.999], 17 iters ---
    float lo = 0.001f, hi = 0.999f;
    for (int it = 0; it < 17; ++it) {
        float mid = 0.5f * (lo + hi);
        Uni U = make_uni(c, mid);
        float iL = 0.f, iD = 0.f;
        if (act) point_LdL(c, U, y, u, iL, iD);
        float sD = iD;
#pragma unroll
        for (int o = 32; o > 0; o >>= 1) sD += __shfl_xor(sD, o, 64);
        if (lane == 0) pB[w] = sD;
        if (t == 0)      spec[0] = iD;
        if (t == 1)      spec[1] = iD;
        if (t == MQ - 1) spec[2] = iD;
        __syncthreads();
        float SD = 0.f;
#pragma unroll
        for (int i = 0; i < 16; ++i) SD += pB[i];
        float dL = trapz_ext(SD, spec[0], spec[1], spec[2]) / PI_F;
        __syncthreads();
        bool p = dL < 0.f;                 // fun(mid) < 0 -> hi = mid
        hi = p ? mid : hi;
        lo = p ? lo : mid;
    }
    float zs_max = 0.5f * (lo + hi);

    // --- bisection 2: root of -V on [0.001, zs_max], 21 iters ---
    lo = 0.001f; hi = zs_max;
    for (int it = 0; it < 21; ++it) {
        float mid = 0.5f * (lo + hi);
        Uni U = make_uni(c, mid);
        float vc = 0.f, vd = 0.f;
        if (act) { vc = point_Vc(c, U, y, u); vd = point_Vd(c, U, y2); }
        float sc = vc, sd = vd;
#pragma unroll
        for (int o = 32; o > 0; o >>= 1) {
            sc += __shfl_xor(sc, o, 64);
            sd += __shfl_xor(sd, o, 64);
        }
        if (lane == 0) { pA[w] = sc; pB[w] = sd; }
        if (t == 0)      { spec[0] = vc; spec[3] = vd; }
        if (t == 1)      { spec[1] = vc; }
        if (t == MQ - 1) { spec[2] = vc; spec[4] = vd; }
        __syncthreads();
        float Sc = 0.f, Sd = 0.f;
#pragma unroll
        for (int i = 0; i < 16; ++i) { Sc += pA[i]; Sd += pB[i]; }
        float Vc = c.coef * PI_F * 4.f * trapz_ext(Sc, spec[0], spec[1], spec[2]) * frcp(mid);
        float Vd = c.coef * PI_F * 2.f * (1.f - mid) * trapz_d(Sd, spec[3], spec[4]);
        __syncthreads();
        bool p = (Vc - Vd) > 0.f;          // (-V) < 0 -> hi = mid
        hi = p ? mid : hi;
        lo = p ? lo : mid;
    }
    float zs_crit = 0.5f * (lo + hi);

    // --- fused final pass: L(zs_max) and L(zs_crit) ---
    {
        Uni Um = make_uni(c, zs_max);
        Uni Uc = make_uni(c, zs_crit);
        float lm = 0.f, lcv = 0.f, dump;
        if (act) {
            float d2;
            point_LdL(c, Um, y, u, lm, dump);
            point_LdL(c, Uc, y, u, lcv, d2);
        }
        float sm = lm, sc2 = lcv;
#pragma unroll
        for (int o = 32; o > 0; o >>= 1) {
            sm  += __shfl_xor(sm, o, 64);
            sc2 += __shfl_xor(sc2, o, 64);
        }
        if (lane == 0) { pA[w] = sm; pB[w] = sc2; }
        if (t == 0)      { spec[0] = lm; spec[3] = lcv; }
        if (t == 1)      { spec[1] = lm; spec[4] = lcv; }
        if (t == MQ - 1) { spec[2] = lm; spec[5] = lcv; }
        __syncthreads();
        if (t == 0) {
            float Sm = 0.f, Sc2 = 0.f;
#pragma unroll
            for (int i = 0; i < 16; ++i) { Sm += pA[i]; Sc2 += pB[i]; }
            float L_max  = 4.f * zs_max  * trapz_ext(Sm,  spec[0], spec[1], spec[2]) / PI_F;
            float L_crit = 4.f * zs_crit * trapz_ext(Sc2, spec[3], spec[4], spec[5]) / PI_F;
            ws[0] = zs_max; ws[1] = L_max; ws[2] = zs_crit; ws[3] = L_crit;
        }
    }
}

// ---------------------------------------------------------------------------
// Kernel 2: per-element Newton + V.  One wave per element, 16 points/lane.
// Toleranced convergence exit: near the fixed point the f32 iterates jitter
// in a few-ulp limit cycle (quadrature noise through (Lz-L)/dL), so exact
// period-1/2 checks never fire (R4/R5: all waves ran the full 25 steps).
// |nzs - zs| <= zs*5e-7 + 1e-8 (~4 ulps) fires ~1 step after convergence and
// adds ~5e-7 relative zs error -> negligible V error.
// j = lane + 64k; j==0,1 -> k=0 lanes 0,1;  j==999 -> k=15 lane 39.
// ---------------------------------------------------------------------------
__global__ __launch_bounds__(256) void newton_v_kernel(
        const float* Ls, const float* a, const float* b, const float* lc,
        const float* ws, float* out, int B) {
    int wid = (blockIdx.x * blockDim.x + threadIdx.x) >> 6;
    int lane = threadIdx.x & 63;
    if (wid >= B) return;

    Co c = make_co(a, b, lc);
    float zs_max = ws[0], L_max = ws[1], L_crit = ws[3];
    float Lq = Ls[wid];
    bool valid = Lq < L_crit;
    float L_eff = valid ? Lq : 0.5f * L_crit;
    float zs = fminf(fmaxf(L_eff * frcp(L_max) * zs_max, 1e-4f), 0.9995f);
    float zs_prev = -1.f;

    for (int step = 0; step < 25; ++step) {
        Uni U = make_uni(c, zs);
        float sL = 0.f, sD = 0.f, l0 = 0.f, d0 = 0.f, lN = 0.f, dN = 0.f;
#pragma unroll
        for (int k = 0; k < 16; ++k) {
            if (k < 15 || lane < 40) {     // j < 1000; constant-true for k<15
                int j = lane + 64 * k;
                float y = fmaf((float)j, DYF, 0.001f);
                float u = 1.f - y * y;
                float iL, iD;
                point_LdL(c, U, y, u, iL, iD);
                sL += iL; sD += iD;
                if (k == 0)  { l0 = iL; d0 = iD; }
                if (k == 15) { lN = iL; dN = iD; }
            }
        }
#pragma unroll
        for (int o = 32; o > 0; o >>= 1) {
            sL += __shfl_xor(sL, o, 64);
            sD += __shfl_xor(sD, o, 64);
        }
        float i0 = __shfl(l0, 0, 64), i1 = __shfl(l0, 1, 64), iN = __shfl(lN, 39, 64);
        float e0 = __shfl(d0, 0, 64), e1 = __shfl(d0, 1, 64), eN = __shfl(dN, 39, 64);
        float Lz = 4.f * zs * trapz_ext(sL, i0, i1, iN) / PI_F;
        float dL = trapz_ext(sD, e0, e1, eN) / PI_F;
        float nzs = fminf(fmaxf(zs - (Lz - L_eff) * frcp(dL), 1e-4f), 0.9995f);
        float tol = fmaf(zs, 5e-7f, 1e-8f);
        if (fabsf(nzs - zs) <= tol) { zs = nzs; break; }   // converged (~4 ulps)
        if (nzs == zs_prev) break;                          // exact 2-cycle
        zs_prev = zs;
        zs = nzs;
    }

    // V(zs)
    Uni U = make_uni(c, zs);
    float sc = 0.f, sd = 0.f, c0 = 0.f, cN = 0.f, q0 = 0.f, qN = 0.f;
#pragma unroll
    for (int k = 0; k < 16; ++k) {
        if (k < 15 || lane < 40) {
            int j = lane + 64 * k;
            float y = fmaf((float)j, DYF, 0.001f);
            float u = 1.f - y * y;
            float vc = point_Vc(c, U, y, u);
            float y2 = fmaf((float)j, DY2F, 0.001f);
            float vd = point_Vd(c, U, y2);
            sc += vc; sd += vd;
            if (k == 0)  { c0 = vc; q0 = vd; }
            if (k == 15) { cN = vc; qN = vd; }
        }
    }
#pragma unroll
    for (int o = 32; o > 0; o >>= 1) {
        sc += __shfl_xor(sc, o, 64);
        sd += __shfl_xor(sd, o, 64);
    }
    float i0 = __shfl(c0, 0, 64), i1 = __shfl(c0, 1, 64), iN = __shfl(cN, 39, 64);
    float p0 = __shfl(q0, 0, 64), pN = __shfl(qN, 39, 64);
    float Vc = c.coef * PI_F * 4.f * trapz_ext(sc, i0, i1, iN) * frcp(zs);
    float Vd = c.coef * PI_F * 2.f * (1.f - zs) * trapz_d(sd, p0, pN);

    if (lane == 0) out[wid] = valid ? (Vc - Vd) : 0.f;
}

// ---------------------------------------------------------------------------
extern "C" void kernel_launch(void* const* d_in, const int* in_sizes, int n_in,
                              void* d_out, int out_size, void* d_ws, size_t ws_size,
                              hipStream_t stream) {
    const float* Ls = (const float*)d_in[0];
    const float* a  = (const float*)d_in[1];
    const float* b  = (const float*)d_in[2];
    const float* lc = (const float*)d_in[3];
    float* out = (float*)d_out;
    float* ws  = (float*)d_ws;
    int B = in_sizes[0];

    solve_scalars_kernel<<<1, 1024, 0, stream>>>(a, b, lc, ws);

    int blocks = (B + 3) / 4;   // 4 waves (elements) per 256-thread block
    newton_v_kernel<<<blocks, 256, 0, stream>>>(Ls, a, b, lc, ws, out, B);
}

// Round 7
// 188.493 us; speedup vs baseline: 1.8169x; 1.6459x over previous
//
#include <hip/hip_runtime.h>
#include <math.h>

#define MQ 1000
#define PI_F 3.14159265358979323846f
#define EPSF 1e-12f
#define DYF  ((float)(0.998/999.0))   // main y-grid step
#define DY2F ((float)(0.999/999.0))   // disconnected y2-grid step (= 0.001)

// fast HW approx ops (v_rcp_f32 / v_rsq_f32 / v_sqrt_f32, ~1 ulp)
__device__ __forceinline__ float frcp(float x)  { return __builtin_amdgcn_rcpf(x); }
__device__ __forceinline__ float frsq(float x)  { return __builtin_amdgcn_rsqf(x); }
__device__ __forceinline__ float fsqrt(float x) { return __builtin_amdgcn_sqrtf(x); }

// ws layout: [0]=zs_max [1]=L_max [2]=zs_crit [3]=L_crit

// ---------------------------------------------------------------------------
// f(z) = 1 + q1 z + q2 z^2 + q3 z^3 + (q4 + cf4 ln z) z^4
// s(z) = 1 + e1 z + e2 z^2 + e3 z^3 + e4 z^4 ;  df = 4(f - s)/z
// eval_b_ = P(z)^2, P = 1 + b0 z + b1 z^2 + p3 z^3, p3 = a0+a1-b0-b1
// g = P^2/(1-z^4);  z dg/g = 2 z P'/P + 4 z^4/(1-z^4);  sqrt(g) = P rsqrt(1-z^4)
// ---------------------------------------------------------------------------
struct Co {
    float q1, q2, q3, q4, cf4;
    float e1, e2, e3, e4;
    float b0, b1, p3;
    float coef;
};

__device__ __forceinline__ Co make_co(const float* a, const float* b, const float* lc) {
    Co c;
    float a0 = a[0], a1 = a[1];
    float cf1 = -8.f * a0 / 3.f;
    float cf2 = -2.f * (2.f * a1 + a0 * a0);
    float cf3 = -8.f * a0 * a1;
    c.cf4 = -4.f * a1 * a1;
    c.q1 = -cf1; c.q2 = -cf2; c.q3 = -cf3; c.q4 = cf1 + cf2 + cf3 - 1.f;
    c.e1 = 2.f * a0;
    c.e2 = 2.f * a1 + a0 * a0;
    c.e3 = 2.f * a0 * a1;
    c.e4 = a1 * a1;
    c.b0 = b[0]; c.b1 = b[1];
    c.p3 = a0 + a1 - b[0] - b[1];
    c.coef = expf(lc[0]);
    return c;
}

struct Uni { float zs, fs, rfs, A4; };

__device__ __forceinline__ Uni make_uni(const Co& c, float zs) {
    Uni U; U.zs = zs;
    float z = zs;
    float lg = __logf(z);
    float t4 = c.q4 + c.cf4 * lg;
    float fz = 1.f + z * (c.q1 + z * (c.q2 + z * (c.q3 + z * t4)));
    float s  = 1.f + z * (c.e1 + z * (c.e2 + z * (c.e3 + z * c.e4)));
    U.fs = fz;
    U.rfs = frcp(fz);
    float dfs = 4.f * (fz - s) * frcp(z);
    U.A4 = zs * dfs * U.rfs - 2.f;     // (zs dfs/fs + 2) - 4
    return U;
}

// L and dL integrands at one point; y and u = 1-y^2 passed in.
__device__ __forceinline__ void point_LdL(const Co& c, const Uni& U,
                                          float y, float u,
                                          float& iL, float& iD) {
    float u2  = u * u;
    float ru2 = frcp(u2);
    float ru4 = ru2 * ru2;
    float z  = U.zs * u;
    float z2 = z * z, z4 = z2 * z2;
    float lg = __logf(z);
    float t4 = c.q4 + c.cf4 * lg;
    float fz = 1.f + z * (c.q1 + z * (c.q2 + z * (c.q3 + z * t4)));
    float s  = 1.f + z * (c.e1 + z * (c.e2 + z * (c.e3 + z * c.e4)));
    float P  = 1.f + z * (c.b0 + z * (c.b1 + z * c.p3));
    float dP = c.b0 + z * (2.f * c.b1 + z * (3.f * c.p3));
    float D  = 1.f - z4;
    float rsqD = frsq(D);
    float rcpD = rsqD * rsqD;
    float rcpP = frcp(P);
    float zdgg = 2.f * z * dP * rcpP + 4.f * z4 * rcpD;   // z dg / g
    float F4 = fz * U.rfs * ru4;                          // r4 * f/fs
    float S4 = s  * U.rfs * ru4;
    float den = fmaxf(F4 - 1.f, EPSF);                    // argL == dL denominator
    float rs  = frsq(den);
    float sqg = P * rsqD;                                 // sqrt(g)
    float t1  = sqg * rs;
    iL = t1 * y;
    float t = F4 * (U.A4 + zdgg) + 4.f * S4 - 2.f - zdgg;
    float rs2 = rs * rs;
    iD = t * (2.f * y) * (t1 * rs2);                      // sqrt(1-z/zs) = y
}

// connected-V integrand
__device__ __forceinline__ float point_Vc(const Co& c, const Uni& U,
                                          float y, float u) {
    float u2  = u * u;
    float u4  = u2 * u2;
    float ru2 = frcp(u2);                                 // 1/w
    float z  = U.zs * u;
    float z2 = z * z, z4 = z2 * z2;
    float lg = __logf(z);
    float t4 = c.q4 + c.cf4 * lg;
    float fz = 1.f + z * (c.q1 + z * (c.q2 + z * (c.q3 + z * t4)));
    float P  = 1.f + z * (c.b0 + z * (c.b1 + z * c.p3));
    float D  = 1.f - z4;
    float rsqD = frsq(D);
    float rcpD = rsqD * rsqD;
    float fg = fz * P * P * rcpD;
    float sqfg = fsqrt(fmaxf(fg, EPSF));
    float rfz = frcp(fz);
    float arg = fmaxf(1.f - u4 * U.fs * rfz, EPSF);       // 1 - w^2/fof
    float t = frsq(arg) - 1.f;
    return sqfg * ru2 * t * y;
}

// disconnected-V integrand on the y2 grid
__device__ __forceinline__ float point_Vd(const Co& c, const Uni& U, float y2) {
    float z  = 1.f - (1.f - U.zs) * y2;
    float z2 = z * z, z4 = z2 * z2;
    float lg = __logf(z);
    float t4 = c.q4 + c.cf4 * lg;
    float fz = 1.f + z * (c.q1 + z * (c.q2 + z * (c.q3 + z * t4)));
    float P  = 1.f + z * (c.b0 + z * (c.b1 + z * c.p3));
    float D  = 1.f - z4;
    float rsqD = frsq(D);
    float fg = fz * P * P * (rsqD * rsqD);
    float sq = fsqrt(fmaxf(fg, EPSF));
    float rz = frcp(z);
    return sq * rz * rz;
}

// trapz over extended grid yy=[0, y..., 1], ii=[v0, integ..., 0]
__device__ __forceinline__ float trapz_ext(float S, float i0, float i1, float iN) {
    float slope = (i1 - i0) * frcp(DYF);
    float v0 = i0 - slope * 0.001f;
    float yLast = 0.001f + 999.f * DYF;
    return DYF * (S - 0.5f * (i0 + iN))
         + 0.5f * (v0 + i0) * 0.001f
         + 0.5f * iN * (1.f - yLast);
}

__device__ __forceinline__ float trapz_d(float S, float q0, float qN) {
    return 0.5f * (1.f + q0) * 0.001f + DY2F * (S - 0.5f * (q0 + qN));
}

// ---------------------------------------------------------------------------
// Kernel 1: root searches by TRISECTION with both candidates evaluated
// concurrently: 1024 threads = 2 candidates x 512 threads x 2 points.
// log2(3) = 1.58 bits/round.  Precision budget: zs_max err ~2e-4 is harmless
// (dL(zs_max) = 0 so L_max is first-order flat; zs_max otherwise only brackets
// search 2) -> 7 rounds.  zs_crit err ~2e-5 only shifts the validity cut,
// where V(zs_crit) = 0 by construction -> 9 rounds.
// Candidate cnd = t>>9 evaluates m = lo + (cnd+1)*(hi-lo)/3 over points
// j = (t&511) and j = (t&511)+512 (< 1000).
// ---------------------------------------------------------------------------
__global__ __launch_bounds__(1024) void solve_scalars_kernel(
        const float* a, const float* b, const float* lc, float* ws) {
    __shared__ float pA[16], pB[16], spec[10];
    Co c = make_co(a, b, lc);
    int t = threadIdx.x;
    int lane = t & 63, w = t >> 6;
    int cnd = t >> 9;          // 0 or 1
    int local = t & 511;
    float y0 = fmaf((float)local, DYF, 0.001f);
    float u0 = 1.f - y0 * y0;
    float y1 = fmaf((float)(local + 512), DYF, 0.001f);
    float u1 = 1.f - y1 * y1;
    bool has2 = (local < 488);          // local+512 < 1000
    float y2a = fmaf((float)local, DY2F, 0.001f);
    float y2b = fmaf((float)(local + 512), DY2F, 0.001f);

    // --- trisection 1: root of dL on [0.001, 0.999], 7 rounds ---
    float lo = 0.001f, hi = 0.999f;
    for (int it = 0; it < 7; ++it) {
        float third = (hi - lo) * (1.f / 3.f);
        float m = fmaf((float)(cnd + 1), third, lo);
        Uni U = make_uni(c, m);
        float iL0, iD0, iL1, iD1 = 0.f;
        point_LdL(c, U, y0, u0, iL0, iD0);
        float sD = iD0;
        if (has2) { point_LdL(c, U, y1, u1, iL1, iD1); sD += iD1; }
#pragma unroll
        for (int o = 32; o > 0; o >>= 1) sD += __shfl_xor(sD, o, 64);
        if (lane == 0) pB[w] = sD;
        if (local == 0)   spec[cnd * 3 + 0] = iD0;
        if (local == 1)   spec[cnd * 3 + 1] = iD0;
        if (local == 487) spec[cnd * 3 + 2] = iD1;
        __syncthreads();
        float SD0 = 0.f, SD1 = 0.f;
#pragma unroll
        for (int i = 0; i < 8; ++i) { SD0 += pB[i]; SD1 += pB[8 + i]; }
        float dL1 = trapz_ext(SD0, spec[0], spec[1], spec[2]) / PI_F;
        float dL2 = trapz_ext(SD1, spec[3], spec[4], spec[5]) / PI_F;
        __syncthreads();
        float m1 = fmaf(1.f, third, lo), m2 = fmaf(2.f, third, lo);
        if (dL1 < 0.f)      { hi = m1; }
        else if (dL2 < 0.f) { lo = m1; hi = m2; }
        else                { lo = m2; }
    }
    float zs_max = 0.5f * (lo + hi);

    // --- trisection 2: root of -V on [0.001, zs_max], 9 rounds ---
    lo = 0.001f; hi = zs_max;
    for (int it = 0; it < 9; ++it) {
        float third = (hi - lo) * (1.f / 3.f);
        float m = fmaf((float)(cnd + 1), third, lo);
        Uni U = make_uni(c, m);
        float vc0 = point_Vc(c, U, y0, u0);
        float vd0 = point_Vd(c, U, y2a);
        float sc = vc0, sd = vd0;
        float vc1 = 0.f, vd1 = 0.f;
        if (has2) {
            vc1 = point_Vc(c, U, y1, u1);
            vd1 = point_Vd(c, U, y2b);
            sc += vc1; sd += vd1;
        }
#pragma unroll
        for (int o = 32; o > 0; o >>= 1) {
            sc += __shfl_xor(sc, o, 64);
            sd += __shfl_xor(sd, o, 64);
        }
        if (lane == 0) { pA[w] = sc; pB[w] = sd; }
        if (local == 0)   { spec[cnd * 5 + 0] = vc0; spec[cnd * 5 + 3] = vd0; }
        if (local == 1)   { spec[cnd * 5 + 1] = vc0; }
        if (local == 487) { spec[cnd * 5 + 2] = vc1; spec[cnd * 5 + 4] = vd1; }
        __syncthreads();
        float Sc0 = 0.f, Sd0 = 0.f, Sc1 = 0.f, Sd1 = 0.f;
#pragma unroll
        for (int i = 0; i < 8; ++i) {
            Sc0 += pA[i]; Sc1 += pA[8 + i];
            Sd0 += pB[i]; Sd1 += pB[8 + i];
        }
        float m1 = fmaf(1.f, third, lo), m2 = fmaf(2.f, third, lo);
        float V1 = c.coef * PI_F * 4.f * trapz_ext(Sc0, spec[0], spec[1], spec[2]) * frcp(m1)
                 - c.coef * PI_F * 2.f * (1.f - m1) * trapz_d(Sd0, spec[3], spec[4]);
        float V2 = c.coef * PI_F * 4.f * trapz_ext(Sc1, spec[5], spec[6], spec[7]) * frcp(m2)
                 - c.coef * PI_F * 2.f * (1.f - m2) * trapz_d(Sd1, spec[8], spec[9]);
        __syncthreads();
        if (V1 > 0.f)      { hi = m1; }          // root left of m1
        else if (V2 > 0.f) { lo = m1; hi = m2; }
        else               { lo = m2; }
    }
    float zs_crit = 0.5f * (lo + hi);

    // --- fused final pass: L(zs_max) and L(zs_crit), 1 pt/thread ---
    {
        bool act = (t < MQ);
        float y = fmaf((float)t, DYF, 0.001f);
        float u = 1.f - y * y;
        Uni Um = make_uni(c, zs_max);
        Uni Uc = make_uni(c, zs_crit);
        float lm = 0.f, lcv = 0.f, dump;
        if (act) {
            float d2;
            point_LdL(c, Um, y, u, lm, dump);
            point_LdL(c, Uc, y, u, lcv, d2);
        }
        float sm = lm, sc2 = lcv;
#pragma unroll
        for (int o = 32; o > 0; o >>= 1) {
            sm  += __shfl_xor(sm, o, 64);
            sc2 += __shfl_xor(sc2, o, 64);
        }
        if (lane == 0) { pA[w] = sm; pB[w] = sc2; }
        if (t == 0)      { spec[0] = lm; spec[3] = lcv; }
        if (t == 1)      { spec[1] = lm; spec[4] = lcv; }
        if (t == MQ - 1) { spec[2] = lm; spec[5] = lcv; }
        __syncthreads();
        if (t == 0) {
            float Sm = 0.f, Sc2 = 0.f;
#pragma unroll
            for (int i = 0; i < 16; ++i) { Sm += pA[i]; Sc2 += pB[i]; }
            float L_max  = 4.f * zs_max  * trapz_ext(Sm,  spec[0], spec[1], spec[2]) / PI_F;
            float L_crit = 4.f * zs_crit * trapz_ext(Sc2, spec[3], spec[4], spec[5]) / PI_F;
            ws[0] = zs_max; ws[1] = L_max; ws[2] = zs_crit; ws[3] = L_crit;
        }
    }
}

// ---------------------------------------------------------------------------
// Kernel 2: per-element Newton + V.  One wave per element, 16 points/lane.
// Exit criteria (R6 post-mortem: dispatch duration = stragglers; the ~4-ulp
// step tolerance never fired for waves whose limit cycle is ~1e-6..1e-5
// relative, so they ran all 25 steps):
//   (a) residual |Lz - L_eff| <= 1e-5*|L_eff| + 1e-8  -> already converged;
//   (b) step |nzs - zs| <= 1e-5*zs + 1e-7             -> converged after step.
// zs error ~1e-5 -> V error O(1), vs threshold 318.
// j = lane + 64k; j==0,1 -> k=0 lanes 0,1;  j==999 -> k=15 lane 39.
// ---------------------------------------------------------------------------
__global__ __launch_bounds__(256) void newton_v_kernel(
        const float* Ls, const float* a, const float* b, const float* lc,
        const float* ws, float* out, int B) {
    int wid = (blockIdx.x * blockDim.x + threadIdx.x) >> 6;
    int lane = threadIdx.x & 63;
    if (wid >= B) return;

    Co c = make_co(a, b, lc);
    float zs_max = ws[0], L_max = ws[1], L_crit = ws[3];
    float Lq = Ls[wid];
    bool valid = Lq < L_crit;
    float L_eff = valid ? Lq : 0.5f * L_crit;
    float zs = fminf(fmaxf(L_eff * frcp(L_max) * zs_max, 1e-4f), 0.9995f);
    float zs_prev = -1.f;

    for (int step = 0; step < 25; ++step) {
        Uni U = make_uni(c, zs);
        float sL = 0.f, sD = 0.f, l0 = 0.f, d0 = 0.f, lN = 0.f, dN = 0.f;
#pragma unroll
        for (int k = 0; k < 16; ++k) {
            if (k < 15 || lane < 40) {     // j < 1000; constant-true for k<15
                int j = lane + 64 * k;
                float y = fmaf((float)j, DYF, 0.001f);
                float u = 1.f - y * y;
                float iL, iD;
                point_LdL(c, U, y, u, iL, iD);
                sL += iL; sD += iD;
                if (k == 0)  { l0 = iL; d0 = iD; }
                if (k == 15) { lN = iL; dN = iD; }
            }
        }
#pragma unroll
        for (int o = 32; o > 0; o >>= 1) {
            sL += __shfl_xor(sL, o, 64);
            sD += __shfl_xor(sD, o, 64);
        }
        float i0 = __shfl(l0, 0, 64), i1 = __shfl(l0, 1, 64), iN = __shfl(lN, 39, 64);
        float e0 = __shfl(d0, 0, 64), e1 = __shfl(d0, 1, 64), eN = __shfl(dN, 39, 64);
        float Lz = 4.f * zs * trapz_ext(sL, i0, i1, iN) / PI_F;
        float dL = trapz_ext(sD, e0, e1, eN) / PI_F;
        // residual exit: current zs already solves L(zs)=L_eff to quadrature noise
        if (fabsf(Lz - L_eff) <= fmaf(fabsf(L_eff), 1e-5f, 1e-8f)) break;
        float nzs = fminf(fmaxf(zs - (Lz - L_eff) * frcp(dL), 1e-4f), 0.9995f);
        if (fabsf(nzs - zs) <= fmaf(zs, 1e-5f, 1e-7f)) { zs = nzs; break; }
        if (nzs == zs_prev) break;                          // exact 2-cycle
        zs_prev = zs;
        zs = nzs;
    }

    // V(zs)
    Uni U = make_uni(c, zs);
    float sc = 0.f, sd = 0.f, c0 = 0.f, cN = 0.f, q0 = 0.f, qN = 0.f;
#pragma unroll
    for (int k = 0; k < 16; ++k) {
        if (k < 15 || lane < 40) {
            int j = lane + 64 * k;
            float y = fmaf((float)j, DYF, 0.001f);
            float u = 1.f - y * y;
            float vc = point_Vc(c, U, y, u);
            float y2 = fmaf((float)j, DY2F, 0.001f);
            float vd = point_Vd(c, U, y2);
            sc += vc; sd += vd;
            if (k == 0)  { c0 = vc; q0 = vd; }
            if (k == 15) { cN = vc; qN = vd; }
        }
    }
#pragma unroll
    for (int o = 32; o > 0; o >>= 1) {
        sc += __shfl_xor(sc, o, 64);
        sd += __shfl_xor(sd, o, 64);
    }
    float i0 = __shfl(c0, 0, 64), i1 = __shfl(c0, 1, 64), iN = __shfl(cN, 39, 64);
    float p0 = __shfl(q0, 0, 64), pN = __shfl(qN, 39, 64);
    float Vc = c.coef * PI_F * 4.f * trapz_ext(sc, i0, i1, iN) * frcp(zs);
    float Vd = c.coef * PI_F * 2.f * (1.f - zs) * trapz_d(sd, p0, pN);

    if (lane == 0) out[wid] = valid ? (Vc - Vd) : 0.f;
}

// ---------------------------------------------------------------------------
extern "C" void kernel_launch(void* const* d_in, const int* in_sizes, int n_in,
                              void* d_out, int out_size, void* d_ws, size_t ws_size,
                              hipStream_t stream) {
    const float* Ls = (const float*)d_in[0];
    const float* a  = (const float*)d_in[1];
    const float* b  = (const float*)d_in[2];
    const float* lc = (const float*)d_in[3];
    float* out = (float*)d_out;
    float* ws  = (float*)d_ws;
    int B = in_sizes[0];

    solve_scalars_kernel<<<1, 1024, 0, stream>>>(a, b, lc, ws);

    int blocks = (B + 3) / 4;   // 4 waves (elements) per 256-thread block
    newton_v_kernel<<<blocks, 256, 0, stream>>>(Ls, a, b, lc, ws, out, B);
}

// Round 8
// 171.354 us; speedup vs baseline: 1.9986x; 1.1000x over previous
//
#include <hip/hip_runtime.h>
#include <math.h>

#define MQ 1000
#define PI_F 3.14159265358979323846f
#define EPSF 1e-12f
#define DYF  ((float)(0.998/999.0))   // main y-grid step
#define DY2F ((float)(0.999/999.0))   // disconnected y2-grid step (= 0.001)

// fast HW approx ops (v_rcp_f32 / v_rsq_f32 / v_sqrt_f32, ~1 ulp)
__device__ __forceinline__ float frcp(float x)  { return __builtin_amdgcn_rcpf(x); }
__device__ __forceinline__ float frsq(float x)  { return __builtin_amdgcn_rsqf(x); }
__device__ __forceinline__ float fsqrt(float x) { return __builtin_amdgcn_sqrtf(x); }

// ws layout: [0]=zs_max [1]=L_max [2]=zs_crit [3]=L_crit

// ---------------------------------------------------------------------------
// f(z) = 1 + q1 z + q2 z^2 + q3 z^3 + (q4 + cf4 ln z) z^4
// s(z) = 1 + e1 z + e2 z^2 + e3 z^3 + e4 z^4 ;  df = 4(f - s)/z
// eval_b_ = P(z)^2, P = 1 + b0 z + b1 z^2 + p3 z^3, p3 = a0+a1-b0-b1
// g = P^2/(1-z^4);  z dg/g = 2 z P'/P + 4 z^4/(1-z^4);  sqrt(g) = P rsqrt(1-z^4)
// ---------------------------------------------------------------------------
struct Co {
    float q1, q2, q3, q4, cf4;
    float e1, e2, e3, e4;
    float b0, b1, p3;
    float coef;
};

__device__ __forceinline__ Co make_co(const float* a, const float* b, const float* lc) {
    Co c;
    float a0 = a[0], a1 = a[1];
    float cf1 = -8.f * a0 / 3.f;
    float cf2 = -2.f * (2.f * a1 + a0 * a0);
    float cf3 = -8.f * a0 * a1;
    c.cf4 = -4.f * a1 * a1;
    c.q1 = -cf1; c.q2 = -cf2; c.q3 = -cf3; c.q4 = cf1 + cf2 + cf3 - 1.f;
    c.e1 = 2.f * a0;
    c.e2 = 2.f * a1 + a0 * a0;
    c.e3 = 2.f * a0 * a1;
    c.e4 = a1 * a1;
    c.b0 = b[0]; c.b1 = b[1];
    c.p3 = a0 + a1 - b[0] - b[1];
    c.coef = expf(lc[0]);
    return c;
}

struct Uni { float zs, fs, rfs, A4; };

__device__ __forceinline__ Uni make_uni(const Co& c, float zs) {
    Uni U; U.zs = zs;
    float z = zs;
    float lg = __logf(z);
    float t4 = c.q4 + c.cf4 * lg;
    float fz = 1.f + z * (c.q1 + z * (c.q2 + z * (c.q3 + z * t4)));
    float s  = 1.f + z * (c.e1 + z * (c.e2 + z * (c.e3 + z * c.e4)));
    U.fs = fz;
    U.rfs = frcp(fz);
    float dfs = 4.f * (fz - s) * frcp(z);
    U.A4 = zs * dfs * U.rfs - 2.f;     // (zs dfs/fs + 2) - 4
    return U;
}

// L and dL integrands at one point; y and u = 1-y^2 passed in.
__device__ __forceinline__ void point_LdL(const Co& c, const Uni& U,
                                          float y, float u,
                                          float& iL, float& iD) {
    float u2  = u * u;
    float ru2 = frcp(u2);
    float ru4 = ru2 * ru2;
    float z  = U.zs * u;
    float z2 = z * z, z4 = z2 * z2;
    float lg = __logf(z);
    float t4 = c.q4 + c.cf4 * lg;
    float fz = 1.f + z * (c.q1 + z * (c.q2 + z * (c.q3 + z * t4)));
    float s  = 1.f + z * (c.e1 + z * (c.e2 + z * (c.e3 + z * c.e4)));
    float P  = 1.f + z * (c.b0 + z * (c.b1 + z * c.p3));
    float dP = c.b0 + z * (2.f * c.b1 + z * (3.f * c.p3));
    float D  = 1.f - z4;
    float rsqD = frsq(D);
    float rcpD = rsqD * rsqD;
    float rcpP = frcp(P);
    float zdgg = 2.f * z * dP * rcpP + 4.f * z4 * rcpD;   // z dg / g
    float F4 = fz * U.rfs * ru4;                          // r4 * f/fs
    float S4 = s  * U.rfs * ru4;
    float den = fmaxf(F4 - 1.f, EPSF);                    // argL == dL denominator
    float rs  = frsq(den);
    float sqg = P * rsqD;                                 // sqrt(g)
    float t1  = sqg * rs;
    iL = t1 * y;
    float t = F4 * (U.A4 + zdgg) + 4.f * S4 - 2.f - zdgg;
    float rs2 = rs * rs;
    iD = t * (2.f * y) * (t1 * rs2);                      // sqrt(1-z/zs) = y
}

// connected-V integrand
__device__ __forceinline__ float point_Vc(const Co& c, const Uni& U,
                                          float y, float u) {
    float u2  = u * u;
    float u4  = u2 * u2;
    float ru2 = frcp(u2);                                 // 1/w
    float z  = U.zs * u;
    float z2 = z * z, z4 = z2 * z2;
    float lg = __logf(z);
    float t4 = c.q4 + c.cf4 * lg;
    float fz = 1.f + z * (c.q1 + z * (c.q2 + z * (c.q3 + z * t4)));
    float P  = 1.f + z * (c.b0 + z * (c.b1 + z * c.p3));
    float D  = 1.f - z4;
    float rsqD = frsq(D);
    float rcpD = rsqD * rsqD;
    float fg = fz * P * P * rcpD;
    float sqfg = fsqrt(fmaxf(fg, EPSF));
    float rfz = frcp(fz);
    float arg = fmaxf(1.f - u4 * U.fs * rfz, EPSF);       // 1 - w^2/fof
    float t = frsq(arg) - 1.f;
    return sqfg * ru2 * t * y;
}

// disconnected-V integrand on the y2 grid
__device__ __forceinline__ float point_Vd(const Co& c, const Uni& U, float y2) {
    float z  = 1.f - (1.f - U.zs) * y2;
    float z2 = z * z, z4 = z2 * z2;
    float lg = __logf(z);
    float t4 = c.q4 + c.cf4 * lg;
    float fz = 1.f + z * (c.q1 + z * (c.q2 + z * (c.q3 + z * t4)));
    float P  = 1.f + z * (c.b0 + z * (c.b1 + z * c.p3));
    float D  = 1.f - z4;
    float rsqD = frsq(D);
    float fg = fz * P * P * (rsqD * rsqD);
    float sq = fsqrt(fmaxf(fg, EPSF));
    float rz = frcp(z);
    return sq * rz * rz;
}

// trapz over extended grid yy=[0, y..., 1], ii=[v0, integ..., 0]
__device__ __forceinline__ float trapz_ext(float S, float i0, float i1, float iN) {
    float slope = (i1 - i0) * frcp(DYF);
    float v0 = i0 - slope * 0.001f;
    float yLast = 0.001f + 999.f * DYF;
    return DYF * (S - 0.5f * (i0 + iN))
         + 0.5f * (v0 + i0) * 0.001f
         + 0.5f * iN * (1.f - yLast);
}

__device__ __forceinline__ float trapz_d(float S, float q0, float qN) {
    return 0.5f * (1.f + q0) * 0.001f + DY2F * (S - 0.5f * (q0 + qN));
}

// ---------------------------------------------------------------------------
// Kernel 1: root searches by TRISECTION with both candidates evaluated
// concurrently: 1024 threads = 2 candidates x 512 threads x 2 points.
// (unchanged from R7)
// ---------------------------------------------------------------------------
__global__ __launch_bounds__(1024) void solve_scalars_kernel(
        const float* a, const float* b, const float* lc, float* ws) {
    __shared__ float pA[16], pB[16], spec[10];
    Co c = make_co(a, b, lc);
    int t = threadIdx.x;
    int lane = t & 63, w = t >> 6;
    int cnd = t >> 9;          // 0 or 1
    int local = t & 511;
    float y0 = fmaf((float)local, DYF, 0.001f);
    float u0 = 1.f - y0 * y0;
    float y1 = fmaf((float)(local + 512), DYF, 0.001f);
    float u1 = 1.f - y1 * y1;
    bool has2 = (local < 488);          // local+512 < 1000
    float y2a = fmaf((float)local, DY2F, 0.001f);
    float y2b = fmaf((float)(local + 512), DY2F, 0.001f);

    // --- trisection 1: root of dL on [0.001, 0.999], 7 rounds ---
    float lo = 0.001f, hi = 0.999f;
    for (int it = 0; it < 7; ++it) {
        float third = (hi - lo) * (1.f / 3.f);
        float m = fmaf((float)(cnd + 1), third, lo);
        Uni U = make_uni(c, m);
        float iL0, iD0, iL1, iD1 = 0.f;
        point_LdL(c, U, y0, u0, iL0, iD0);
        float sD = iD0;
        if (has2) { point_LdL(c, U, y1, u1, iL1, iD1); sD += iD1; }
#pragma unroll
        for (int o = 32; o > 0; o >>= 1) sD += __shfl_xor(sD, o, 64);
        if (lane == 0) pB[w] = sD;
        if (local == 0)   spec[cnd * 3 + 0] = iD0;
        if (local == 1)   spec[cnd * 3 + 1] = iD0;
        if (local == 487) spec[cnd * 3 + 2] = iD1;
        __syncthreads();
        float SD0 = 0.f, SD1 = 0.f;
#pragma unroll
        for (int i = 0; i < 8; ++i) { SD0 += pB[i]; SD1 += pB[8 + i]; }
        float dL1 = trapz_ext(SD0, spec[0], spec[1], spec[2]) / PI_F;
        float dL2 = trapz_ext(SD1, spec[3], spec[4], spec[5]) / PI_F;
        __syncthreads();
        float m1 = fmaf(1.f, third, lo), m2 = fmaf(2.f, third, lo);
        if (dL1 < 0.f)      { hi = m1; }
        else if (dL2 < 0.f) { lo = m1; hi = m2; }
        else                { lo = m2; }
    }
    float zs_max = 0.5f * (lo + hi);

    // --- trisection 2: root of -V on [0.001, zs_max], 9 rounds ---
    lo = 0.001f; hi = zs_max;
    for (int it = 0; it < 9; ++it) {
        float third = (hi - lo) * (1.f / 3.f);
        float m = fmaf((float)(cnd + 1), third, lo);
        Uni U = make_uni(c, m);
        float vc0 = point_Vc(c, U, y0, u0);
        float vd0 = point_Vd(c, U, y2a);
        float sc = vc0, sd = vd0;
        float vc1 = 0.f, vd1 = 0.f;
        if (has2) {
            vc1 = point_Vc(c, U, y1, u1);
            vd1 = point_Vd(c, U, y2b);
            sc += vc1; sd += vd1;
        }
#pragma unroll
        for (int o = 32; o > 0; o >>= 1) {
            sc += __shfl_xor(sc, o, 64);
            sd += __shfl_xor(sd, o, 64);
        }
        if (lane == 0) { pA[w] = sc; pB[w] = sd; }
        if (local == 0)   { spec[cnd * 5 + 0] = vc0; spec[cnd * 5 + 3] = vd0; }
        if (local == 1)   { spec[cnd * 5 + 1] = vc0; }
        if (local == 487) { spec[cnd * 5 + 2] = vc1; spec[cnd * 5 + 4] = vd1; }
        __syncthreads();
        float Sc0 = 0.f, Sd0 = 0.f, Sc1 = 0.f, Sd1 = 0.f;
#pragma unroll
        for (int i = 0; i < 8; ++i) {
            Sc0 += pA[i]; Sc1 += pA[8 + i];
            Sd0 += pB[i]; Sd1 += pB[8 + i];
        }
        float m1 = fmaf(1.f, third, lo), m2 = fmaf(2.f, third, lo);
        float V1 = c.coef * PI_F * 4.f * trapz_ext(Sc0, spec[0], spec[1], spec[2]) * frcp(m1)
                 - c.coef * PI_F * 2.f * (1.f - m1) * trapz_d(Sd0, spec[3], spec[4]);
        float V2 = c.coef * PI_F * 4.f * trapz_ext(Sc1, spec[5], spec[6], spec[7]) * frcp(m2)
                 - c.coef * PI_F * 2.f * (1.f - m2) * trapz_d(Sd1, spec[8], spec[9]);
        __syncthreads();
        if (V1 > 0.f)      { hi = m1; }          // root left of m1
        else if (V2 > 0.f) { lo = m1; hi = m2; }
        else               { lo = m2; }
    }
    float zs_crit = 0.5f * (lo + hi);

    // --- fused final pass: L(zs_max) and L(zs_crit), 1 pt/thread ---
    {
        bool act = (t < MQ);
        float y = fmaf((float)t, DYF, 0.001f);
        float u = 1.f - y * y;
        Uni Um = make_uni(c, zs_max);
        Uni Uc = make_uni(c, zs_crit);
        float lm = 0.f, lcv = 0.f, dump;
        if (act) {
            float d2;
            point_LdL(c, Um, y, u, lm, dump);
            point_LdL(c, Uc, y, u, lcv, d2);
        }
        float sm = lm, sc2 = lcv;
#pragma unroll
        for (int o = 32; o > 0; o >>= 1) {
            sm  += __shfl_xor(sm, o, 64);
            sc2 += __shfl_xor(sc2, o, 64);
        }
        if (lane == 0) { pA[w] = sm; pB[w] = sc2; }
        if (t == 0)      { spec[0] = lm; spec[3] = lcv; }
        if (t == 1)      { spec[1] = lm; spec[4] = lcv; }
        if (t == MQ - 1) { spec[2] = lm; spec[5] = lcv; }
        __syncthreads();
        if (t == 0) {
            float Sm = 0.f, Sc2 = 0.f;
#pragma unroll
            for (int i = 0; i < 16; ++i) { Sm += pA[i]; Sc2 += pB[i]; }
            float L_max  = 4.f * zs_max  * trapz_ext(Sm,  spec[0], spec[1], spec[2]) / PI_F;
            float L_crit = 4.f * zs_crit * trapz_ext(Sc2, spec[3], spec[4], spec[5]) / PI_F;
            ws[0] = zs_max; ws[1] = L_max; ws[2] = zs_crit; ws[3] = L_crit;
        }
    }
}

// ---------------------------------------------------------------------------
// Kernel 2: per-element Newton + V.  One wave per element, 16 points/lane.
// R8 changes:
//   (1) invalid rows (Ls >= L_crit) output exactly 0 in the reference ->
//       skip Newton + V entirely (exact, wave-uniform early return);
//   (2) stall exit: track best residual |Lz - L_eff| and its zs; if the
//       residual fails to improve for 2 consecutive steps, the iterate is at
//       its quadrature-noise floor (R7 stragglers: limit-cycle amplitude >
//       1e-5 tolerance where dL is small, so tolerance exits never fired and
//       whole SIMDs ran all 25 steps) -> exit with the best-residual zs,
//       which is at least as accurate as the last iterate.
// j = lane + 64k; j==0,1 -> k=0 lanes 0,1;  j==999 -> k=15 lane 39.
// ---------------------------------------------------------------------------
__global__ __launch_bounds__(256) void newton_v_kernel(
        const float* Ls, const float* a, const float* b, const float* lc,
        const float* ws, float* out, int B) {
    int wid = (blockIdx.x * blockDim.x + threadIdx.x) >> 6;
    int lane = threadIdx.x & 63;
    if (wid >= B) return;

    float L_crit = ws[3];
    float Lq = Ls[wid];
    if (!(Lq < L_crit)) {              // invalid row: exact 0, skip all work
        if (lane == 0) out[wid] = 0.f;
        return;
    }

    Co c = make_co(a, b, lc);
    float zs_max = ws[0], L_max = ws[1];
    float L_eff = Lq;
    float zs = fminf(fmaxf(L_eff * frcp(L_max) * zs_max, 1e-4f), 0.9995f);
    float zs_prev = -1.f;
    float best_res = 1e30f, zs_best = zs;
    int stall = 0;

    for (int step = 0; step < 25; ++step) {
        Uni U = make_uni(c, zs);
        float sL = 0.f, sD = 0.f, l0 = 0.f, d0 = 0.f, lN = 0.f, dN = 0.f;
#pragma unroll
        for (int k = 0; k < 16; ++k) {
            if (k < 15 || lane < 40) {     // j < 1000; constant-true for k<15
                int j = lane + 64 * k;
                float y = fmaf((float)j, DYF, 0.001f);
                float u = 1.f - y * y;
                float iL, iD;
                point_LdL(c, U, y, u, iL, iD);
                sL += iL; sD += iD;
                if (k == 0)  { l0 = iL; d0 = iD; }
                if (k == 15) { lN = iL; dN = iD; }
            }
        }
#pragma unroll
        for (int o = 32; o > 0; o >>= 1) {
            sL += __shfl_xor(sL, o, 64);
            sD += __shfl_xor(sD, o, 64);
        }
        float i0 = __shfl(l0, 0, 64), i1 = __shfl(l0, 1, 64), iN = __shfl(lN, 39, 64);
        float e0 = __shfl(d0, 0, 64), e1 = __shfl(d0, 1, 64), eN = __shfl(dN, 39, 64);
        float Lz = 4.f * zs * trapz_ext(sL, i0, i1, iN) / PI_F;
        float dL = trapz_ext(sD, e0, e1, eN) / PI_F;
        float res = fabsf(Lz - L_eff);
        // residual exit: zs already solves L(zs)=L_eff to quadrature noise
        if (res <= fmaf(L_eff, 1e-5f, 1e-8f)) break;
        // stall exit: residual no longer improving -> noise floor reached
        if (res < best_res) { best_res = res; zs_best = zs; stall = 0; }
        else if (++stall >= 2) { zs = zs_best; break; }
        float nzs = fminf(fmaxf(zs - (Lz - L_eff) * frcp(dL), 1e-4f), 0.9995f);
        if (fabsf(nzs - zs) <= fmaf(zs, 1e-5f, 1e-7f)) { zs = nzs; break; }
        if (nzs == zs_prev) break;                          // exact 2-cycle
        zs_prev = zs;
        zs = nzs;
    }

    // V(zs)
    Uni U = make_uni(c, zs);
    float sc = 0.f, sd = 0.f, c0 = 0.f, cN = 0.f, q0 = 0.f, qN = 0.f;
#pragma unroll
    for (int k = 0; k < 16; ++k) {
        if (k < 15 || lane < 40) {
            int j = lane + 64 * k;
            float y = fmaf((float)j, DYF, 0.001f);
            float u = 1.f - y * y;
            float vc = point_Vc(c, U, y, u);
            float y2 = fmaf((float)j, DY2F, 0.001f);
            float vd = point_Vd(c, U, y2);
            sc += vc; sd += vd;
            if (k == 0)  { c0 = vc; q0 = vd; }
            if (k == 15) { cN = vc; qN = vd; }
        }
    }
#pragma unroll
    for (int o = 32; o > 0; o >>= 1) {
        sc += __shfl_xor(sc, o, 64);
        sd += __shfl_xor(sd, o, 64);
    }
    float i0 = __shfl(c0, 0, 64), i1 = __shfl(c0, 1, 64), iN = __shfl(cN, 39, 64);
    float p0 = __shfl(q0, 0, 64), pN = __shfl(qN, 39, 64);
    float Vc = c.coef * PI_F * 4.f * trapz_ext(sc, i0, i1, iN) * frcp(zs);
    float Vd = c.coef * PI_F * 2.f * (1.f - zs) * trapz_d(sd, p0, pN);

    if (lane == 0) out[wid] = Vc - Vd;
}

// ---------------------------------------------------------------------------
extern "C" void kernel_launch(void* const* d_in, const int* in_sizes, int n_in,
                              void* d_out, int out_size, void* d_ws, size_t ws_size,
                              hipStream_t stream) {
    const float* Ls = (const float*)d_in[0];
    const float* a  = (const float*)d_in[1];
    const float* b  = (const float*)d_in[2];
    const float* lc = (const float*)d_in[3];
    float* out = (float*)d_out;
    float* ws  = (float*)d_ws;
    int B = in_sizes[0];

    solve_scalars_kernel<<<1, 1024, 0, stream>>>(a, b, lc, ws);

    int blocks = (B + 3) / 4;   // 4 waves (elements) per 256-thread block
    newton_v_kernel<<<blocks, 256, 0, stream>>>(Ls, a, b, lc, ws, out, B);
}

// Round 9
// 156.723 us; speedup vs baseline: 2.1852x; 1.0934x over previous
//
#include <hip/hip_runtime.h>
#include <math.h>

#define MQ 1000
#define PI_F 3.14159265358979323846f
#define EPSF 1e-12f
#define DYF  ((float)(0.998/999.0))   // main y-grid step
#define DY2F ((float)(0.999/999.0))   // disconnected y2-grid step (= 0.001)

// fast HW approx ops (v_rcp_f32 / v_rsq_f32 / v_sqrt_f32, ~1 ulp)
__device__ __forceinline__ float frcp(float x)  { return __builtin_amdgcn_rcpf(x); }
__device__ __forceinline__ float frsq(float x)  { return __builtin_amdgcn_rsqf(x); }
__device__ __forceinline__ float fsqrt(float x) { return __builtin_amdgcn_sqrtf(x); }

// ws layout: [0]=zs_max [1]=L_max [2]=zs_crit [3]=L_crit

// ---------------------------------------------------------------------------
// f(z) = 1 + q1 z + q2 z^2 + q3 z^3 + (q4 + cf4 ln z) z^4
// s(z) = 1 + e1 z + e2 z^2 + e3 z^3 + e4 z^4 ;  df = 4(f - s)/z
// eval_b_ = P(z)^2, P = 1 + b0 z + b1 z^2 + p3 z^3, p3 = a0+a1-b0-b1
// g = P^2/(1-z^4);  z dg/g = 2 z P'/P + 4 z^4/(1-z^4);  sqrt(g) = P rsqrt(1-z^4)
// ---------------------------------------------------------------------------
struct Co {
    float q1, q2, q3, q4, cf4;
    float e1, e2, e3, e4;
    float b0, b1, p3;
    float coef;
};

__device__ __forceinline__ Co make_co(const float* a, const float* b, const float* lc) {
    Co c;
    float a0 = a[0], a1 = a[1];
    float cf1 = -8.f * a0 / 3.f;
    float cf2 = -2.f * (2.f * a1 + a0 * a0);
    float cf3 = -8.f * a0 * a1;
    c.cf4 = -4.f * a1 * a1;
    c.q1 = -cf1; c.q2 = -cf2; c.q3 = -cf3; c.q4 = cf1 + cf2 + cf3 - 1.f;
    c.e1 = 2.f * a0;
    c.e2 = 2.f * a1 + a0 * a0;
    c.e3 = 2.f * a0 * a1;
    c.e4 = a1 * a1;
    c.b0 = b[0]; c.b1 = b[1];
    c.p3 = a0 + a1 - b[0] - b[1];
    c.coef = expf(lc[0]);
    return c;
}

struct Uni { float zs, fs, rfs, A4; };

__device__ __forceinline__ Uni make_uni(const Co& c, float zs) {
    Uni U; U.zs = zs;
    float z = zs;
    float lg = __logf(z);
    float t4 = c.q4 + c.cf4 * lg;
    float fz = 1.f + z * (c.q1 + z * (c.q2 + z * (c.q3 + z * t4)));
    float s  = 1.f + z * (c.e1 + z * (c.e2 + z * (c.e3 + z * c.e4)));
    U.fs = fz;
    U.rfs = frcp(fz);
    float dfs = 4.f * (fz - s) * frcp(z);
    U.A4 = zs * dfs * U.rfs - 2.f;     // (zs dfs/fs + 2) - 4
    return U;
}

// L and dL integrands at one point; y and u = 1-y^2 passed in.
__device__ __forceinline__ void point_LdL(const Co& c, const Uni& U,
                                          float y, float u,
                                          float& iL, float& iD) {
    float u2  = u * u;
    float ru2 = frcp(u2);
    float ru4 = ru2 * ru2;
    float z  = U.zs * u;
    float z2 = z * z, z4 = z2 * z2;
    float lg = __logf(z);
    float t4 = c.q4 + c.cf4 * lg;
    float fz = 1.f + z * (c.q1 + z * (c.q2 + z * (c.q3 + z * t4)));
    float s  = 1.f + z * (c.e1 + z * (c.e2 + z * (c.e3 + z * c.e4)));
    float P  = 1.f + z * (c.b0 + z * (c.b1 + z * c.p3));
    float dP = c.b0 + z * (2.f * c.b1 + z * (3.f * c.p3));
    float D  = 1.f - z4;
    float rsqD = frsq(D);
    float rcpD = rsqD * rsqD;
    float rcpP = frcp(P);
    float zdgg = 2.f * z * dP * rcpP + 4.f * z4 * rcpD;   // z dg / g
    float F4 = fz * U.rfs * ru4;                          // r4 * f/fs
    float S4 = s  * U.rfs * ru4;
    float den = fmaxf(F4 - 1.f, EPSF);                    // argL == dL denominator
    float rs  = frsq(den);
    float sqg = P * rsqD;                                 // sqrt(g)
    float t1  = sqg * rs;
    iL = t1 * y;
    float t = F4 * (U.A4 + zdgg) + 4.f * S4 - 2.f - zdgg;
    float rs2 = rs * rs;
    iD = t * (2.f * y) * (t1 * rs2);                      // sqrt(1-z/zs) = y
}

// connected-V integrand
__device__ __forceinline__ float point_Vc(const Co& c, const Uni& U,
                                          float y, float u) {
    float u2  = u * u;
    float u4  = u2 * u2;
    float ru2 = frcp(u2);                                 // 1/w
    float z  = U.zs * u;
    float z2 = z * z, z4 = z2 * z2;
    float lg = __logf(z);
    float t4 = c.q4 + c.cf4 * lg;
    float fz = 1.f + z * (c.q1 + z * (c.q2 + z * (c.q3 + z * t4)));
    float P  = 1.f + z * (c.b0 + z * (c.b1 + z * c.p3));
    float D  = 1.f - z4;
    float rsqD = frsq(D);
    float rcpD = rsqD * rsqD;
    float fg = fz * P * P * rcpD;
    float sqfg = fsqrt(fmaxf(fg, EPSF));
    float rfz = frcp(fz);
    float arg = fmaxf(1.f - u4 * U.fs * rfz, EPSF);       // 1 - w^2/fof
    float t = frsq(arg) - 1.f;
    return sqfg * ru2 * t * y;
}

// disconnected-V integrand on the y2 grid
__device__ __forceinline__ float point_Vd(const Co& c, const Uni& U, float y2) {
    float z  = 1.f - (1.f - U.zs) * y2;
    float z2 = z * z, z4 = z2 * z2;
    float lg = __logf(z);
    float t4 = c.q4 + c.cf4 * lg;
    float fz = 1.f + z * (c.q1 + z * (c.q2 + z * (c.q3 + z * t4)));
    float P  = 1.f + z * (c.b0 + z * (c.b1 + z * c.p3));
    float D  = 1.f - z4;
    float rsqD = frsq(D);
    float fg = fz * P * P * (rsqD * rsqD);
    float sq = fsqrt(fmaxf(fg, EPSF));
    float rz = frcp(z);
    return sq * rz * rz;
}

// trapz over extended grid yy=[0, y..., 1], ii=[v0, integ..., 0]
__device__ __forceinline__ float trapz_ext(float S, float i0, float i1, float iN) {
    float slope = (i1 - i0) * frcp(DYF);
    float v0 = i0 - slope * 0.001f;
    float yLast = 0.001f + 999.f * DYF;
    return DYF * (S - 0.5f * (i0 + iN))
         + 0.5f * (v0 + i0) * 0.001f
         + 0.5f * iN * (1.f - yLast);
}

__device__ __forceinline__ float trapz_d(float S, float q0, float qN) {
    return 0.5f * (1.f + q0) * 0.001f + DY2F * (S - 0.5f * (q0 + qN));
}

// ---------------------------------------------------------------------------
// Kernel 1: root searches by TRISECTION with both candidates evaluated
// concurrently: 1024 threads = 2 candidates x 512 threads x 2 points.
// (unchanged from R8; measured cost ~10 us, poor ROI for further work)
// ---------------------------------------------------------------------------
__global__ __launch_bounds__(1024) void solve_scalars_kernel(
        const float* a, const float* b, const float* lc, float* ws) {
    __shared__ float pA[16], pB[16], spec[10];
    Co c = make_co(a, b, lc);
    int t = threadIdx.x;
    int lane = t & 63, w = t >> 6;
    int cnd = t >> 9;          // 0 or 1
    int local = t & 511;
    float y0 = fmaf((float)local, DYF, 0.001f);
    float u0 = 1.f - y0 * y0;
    float y1 = fmaf((float)(local + 512), DYF, 0.001f);
    float u1 = 1.f - y1 * y1;
    bool has2 = (local < 488);          // local+512 < 1000
    float y2a = fmaf((float)local, DY2F, 0.001f);
    float y2b = fmaf((float)(local + 512), DY2F, 0.001f);

    // --- trisection 1: root of dL on [0.001, 0.999], 7 rounds ---
    float lo = 0.001f, hi = 0.999f;
    for (int it = 0; it < 7; ++it) {
        float third = (hi - lo) * (1.f / 3.f);
        float m = fmaf((float)(cnd + 1), third, lo);
        Uni U = make_uni(c, m);
        float iL0, iD0, iL1, iD1 = 0.f;
        point_LdL(c, U, y0, u0, iL0, iD0);
        float sD = iD0;
        if (has2) { point_LdL(c, U, y1, u1, iL1, iD1); sD += iD1; }
#pragma unroll
        for (int o = 32; o > 0; o >>= 1) sD += __shfl_xor(sD, o, 64);
        if (lane == 0) pB[w] = sD;
        if (local == 0)   spec[cnd * 3 + 0] = iD0;
        if (local == 1)   spec[cnd * 3 + 1] = iD0;
        if (local == 487) spec[cnd * 3 + 2] = iD1;
        __syncthreads();
        float SD0 = 0.f, SD1 = 0.f;
#pragma unroll
        for (int i = 0; i < 8; ++i) { SD0 += pB[i]; SD1 += pB[8 + i]; }
        float dL1 = trapz_ext(SD0, spec[0], spec[1], spec[2]) / PI_F;
        float dL2 = trapz_ext(SD1, spec[3], spec[4], spec[5]) / PI_F;
        __syncthreads();
        float m1 = fmaf(1.f, third, lo), m2 = fmaf(2.f, third, lo);
        if (dL1 < 0.f)      { hi = m1; }
        else if (dL2 < 0.f) { lo = m1; hi = m2; }
        else                { lo = m2; }
    }
    float zs_max = 0.5f * (lo + hi);

    // --- trisection 2: root of -V on [0.001, zs_max], 9 rounds ---
    lo = 0.001f; hi = zs_max;
    for (int it = 0; it < 9; ++it) {
        float third = (hi - lo) * (1.f / 3.f);
        float m = fmaf((float)(cnd + 1), third, lo);
        Uni U = make_uni(c, m);
        float vc0 = point_Vc(c, U, y0, u0);
        float vd0 = point_Vd(c, U, y2a);
        float sc = vc0, sd = vd0;
        float vc1 = 0.f, vd1 = 0.f;
        if (has2) {
            vc1 = point_Vc(c, U, y1, u1);
            vd1 = point_Vd(c, U, y2b);
            sc += vc1; sd += vd1;
        }
#pragma unroll
        for (int o = 32; o > 0; o >>= 1) {
            sc += __shfl_xor(sc, o, 64);
            sd += __shfl_xor(sd, o, 64);
        }
        if (lane == 0) { pA[w] = sc; pB[w] = sd; }
        if (local == 0)   { spec[cnd * 5 + 0] = vc0; spec[cnd * 5 + 3] = vd0; }
        if (local == 1)   { spec[cnd * 5 + 1] = vc0; }
        if (local == 487) { spec[cnd * 5 + 2] = vc1; spec[cnd * 5 + 4] = vd1; }
        __syncthreads();
        float Sc0 = 0.f, Sd0 = 0.f, Sc1 = 0.f, Sd1 = 0.f;
#pragma unroll
        for (int i = 0; i < 8; ++i) {
            Sc0 += pA[i]; Sc1 += pA[8 + i];
            Sd0 += pB[i]; Sd1 += pB[8 + i];
        }
        float m1 = fmaf(1.f, third, lo), m2 = fmaf(2.f, third, lo);
        float V1 = c.coef * PI_F * 4.f * trapz_ext(Sc0, spec[0], spec[1], spec[2]) * frcp(m1)
                 - c.coef * PI_F * 2.f * (1.f - m1) * trapz_d(Sd0, spec[3], spec[4]);
        float V2 = c.coef * PI_F * 4.f * trapz_ext(Sc1, spec[5], spec[6], spec[7]) * frcp(m2)
                 - c.coef * PI_F * 2.f * (1.f - m2) * trapz_d(Sd1, spec[8], spec[9]);
        __syncthreads();
        if (V1 > 0.f)      { hi = m1; }          // root left of m1
        else if (V2 > 0.f) { lo = m1; hi = m2; }
        else               { lo = m2; }
    }
    float zs_crit = 0.5f * (lo + hi);

    // --- fused final pass: L(zs_max) and L(zs_crit), 1 pt/thread ---
    {
        bool act = (t < MQ);
        float y = fmaf((float)t, DYF, 0.001f);
        float u = 1.f - y * y;
        Uni Um = make_uni(c, zs_max);
        Uni Uc = make_uni(c, zs_crit);
        float lm = 0.f, lcv = 0.f, dump;
        if (act) {
            float d2;
            point_LdL(c, Um, y, u, lm, dump);
            point_LdL(c, Uc, y, u, lcv, d2);
        }
        float sm = lm, sc2 = lcv;
#pragma unroll
        for (int o = 32; o > 0; o >>= 1) {
            sm  += __shfl_xor(sm, o, 64);
            sc2 += __shfl_xor(sc2, o, 64);
        }
        if (lane == 0) { pA[w] = sm; pB[w] = sc2; }
        if (t == 0)      { spec[0] = lm; spec[3] = lcv; }
        if (t == 1)      { spec[1] = lm; spec[4] = lcv; }
        if (t == MQ - 1) { spec[2] = lm; spec[5] = lcv; }
        __syncthreads();
        if (t == 0) {
            float Sm = 0.f, Sc2 = 0.f;
#pragma unroll
            for (int i = 0; i < 16; ++i) { Sm += pA[i]; Sc2 += pB[i]; }
            float L_max  = 4.f * zs_max  * trapz_ext(Sm,  spec[0], spec[1], spec[2]) / PI_F;
            float L_crit = 4.f * zs_crit * trapz_ext(Sc2, spec[3], spec[4], spec[5]) / PI_F;
            ws[0] = zs_max; ws[1] = L_max; ws[2] = zs_crit; ws[3] = L_crit;
        }
    }
}

// ---------------------------------------------------------------------------
// Kernel 2: per-element Newton + V.  One wave per element, 16 points/lane.
// R9 changes (straggler tail = slow-LINEAR convergers near L_crit where dL
// is small; their residual improves a little every step so neither the
// tolerance nor the pure stall exit ever fired -> full 25 steps):
//   (1) chord init through (L_crit, zs_crit): valid elements have
//       L_eff < L_crit, and init error -> 0 exactly where conditioning is
//       worst (L_eff -> L_crit);
//   (2) slow-progress exit: converging Newton shrinks res >>2x/step; if
//       res >= 0.5*best_res twice in a row, we're at the noise floor ->
//       exit with the best-res iterate;
//   (3) hard cap 14 steps (keep best-res zs).
// j = lane + 64k; j==0,1 -> k=0 lanes 0,1;  j==999 -> k=15 lane 39.
// ---------------------------------------------------------------------------
__global__ __launch_bounds__(256) void newton_v_kernel(
        const float* Ls, const float* a, const float* b, const float* lc,
        const float* ws, float* out, int B) {
    int wid = (blockIdx.x * blockDim.x + threadIdx.x) >> 6;
    int lane = threadIdx.x & 63;
    if (wid >= B) return;

    float L_crit = ws[3];
    float Lq = Ls[wid];
    if (!(Lq < L_crit)) {              // invalid row: exact 0, skip all work
        if (lane == 0) out[wid] = 0.f;
        return;
    }

    Co c = make_co(a, b, lc);
    float zs_crit = ws[2];
    float L_eff = Lq;
    // chord through (0,0)-(L_crit, zs_crit); all valid L_eff lie inside it
    float zs = fminf(fmaxf(L_eff * frcp(L_crit) * zs_crit, 1e-4f), 0.9995f);
    float zs_prev = -1.f;
    float best_res = 1e30f, zs_best = zs;
    int stall = 0;

    for (int step = 0; step < 14; ++step) {
        Uni U = make_uni(c, zs);
        float sL = 0.f, sD = 0.f, l0 = 0.f, d0 = 0.f, lN = 0.f, dN = 0.f;
#pragma unroll
        for (int k = 0; k < 16; ++k) {
            if (k < 15 || lane < 40) {     // j < 1000; constant-true for k<15
                int j = lane + 64 * k;
                float y = fmaf((float)j, DYF, 0.001f);
                float u = 1.f - y * y;
                float iL, iD;
                point_LdL(c, U, y, u, iL, iD);
                sL += iL; sD += iD;
                if (k == 0)  { l0 = iL; d0 = iD; }
                if (k == 15) { lN = iL; dN = iD; }
            }
        }
#pragma unroll
        for (int o = 32; o > 0; o >>= 1) {
            sL += __shfl_xor(sL, o, 64);
            sD += __shfl_xor(sD, o, 64);
        }
        float i0 = __shfl(l0, 0, 64), i1 = __shfl(l0, 1, 64), iN = __shfl(lN, 39, 64);
        float e0 = __shfl(d0, 0, 64), e1 = __shfl(d0, 1, 64), eN = __shfl(dN, 39, 64);
        float Lz = 4.f * zs * trapz_ext(sL, i0, i1, iN) / PI_F;
        float dL = trapz_ext(sD, e0, e1, eN) / PI_F;
        float res = fabsf(Lz - L_eff);
        // residual exit: zs already solves L(zs)=L_eff to quadrature noise
        if (res <= fmaf(L_eff, 1e-5f, 1e-8f)) break;
        // slow-progress / stall exit: noise floor or slow-linear regime
        if (res < 0.5f * best_res) {
            if (res < best_res) { best_res = res; zs_best = zs; }
            stall = 0;
        } else {
            if (res < best_res) { best_res = res; zs_best = zs; }
            if (++stall >= 2) { zs = zs_best; break; }
        }
        float nzs = fminf(fmaxf(zs - (Lz - L_eff) * frcp(dL), 1e-4f), 0.9995f);
        if (fabsf(nzs - zs) <= fmaf(zs, 1e-5f, 1e-7f)) { zs = nzs; break; }
        if (nzs == zs_prev) break;                          // exact 2-cycle
        zs_prev = zs;
        zs = nzs;
    }

    // V(zs)
    Uni U = make_uni(c, zs);
    float sc = 0.f, sd = 0.f, c0 = 0.f, cN = 0.f, q0 = 0.f, qN = 0.f;
#pragma unroll
    for (int k = 0; k < 16; ++k) {
        if (k < 15 || lane < 40) {
            int j = lane + 64 * k;
            float y = fmaf((float)j, DYF, 0.001f);
            float u = 1.f - y * y;
            float vc = point_Vc(c, U, y, u);
            float y2 = fmaf((float)j, DY2F, 0.001f);
            float vd = point_Vd(c, U, y2);
            sc += vc; sd += vd;
            if (k == 0)  { c0 = vc; q0 = vd; }
            if (k == 15) { cN = vc; qN = vd; }
        }
    }
#pragma unroll
    for (int o = 32; o > 0; o >>= 1) {
        sc += __shfl_xor(sc, o, 64);
        sd += __shfl_xor(sd, o, 64);
    }
    float i0 = __shfl(c0, 0, 64), i1 = __shfl(c0, 1, 64), iN = __shfl(cN, 39, 64);
    float p0 = __shfl(q0, 0, 64), pN = __shfl(qN, 39, 64);
    float Vc = c.coef * PI_F * 4.f * trapz_ext(sc, i0, i1, iN) * frcp(zs);
    float Vd = c.coef * PI_F * 2.f * (1.f - zs) * trapz_d(sd, p0, pN);

    if (lane == 0) out[wid] = Vc - Vd;
}

// ---------------------------------------------------------------------------
extern "C" void kernel_launch(void* const* d_in, const int* in_sizes, int n_in,
                              void* d_out, int out_size, void* d_ws, size_t ws_size,
                              hipStream_t stream) {
    const float* Ls = (const float*)d_in[0];
    const float* a  = (const float*)d_in[1];
    const float* b  = (const float*)d_in[2];
    const float* lc = (const float*)d_in[3];
    float* out = (float*)d_out;
    float* ws  = (float*)d_ws;
    int B = in_sizes[0];

    solve_scalars_kernel<<<1, 1024, 0, stream>>>(a, b, lc, ws);

    int blocks = (B + 3) / 4;   // 4 waves (elements) per 256-thread block
    newton_v_kernel<<<blocks, 256, 0, stream>>>(Ls, a, b, lc, ws, out, B);
}